// Round 16
// baseline (140.281 us; speedup 1.0000x reference)
//
#include <hip/hip_runtime.h>

// Problem dims (fixed by reference)
#define T_TOTAL (32 * 4096)   // B*S = 131072 tokens
#define FDIM 256
#define NG 2                  // groups
#define NN 128                // entries per group
#define DDIM 128              // group dim
#define EDIM 256              // embed dim

#define TAU 0.004f            // bf16x3-vs-f32 safety margin for argmax gap
#define CAP 16384             // max flagged (t,g) entries (expected ~1k)

#define GROW 132              // padded gumbel LDS row (floats): breaks bank alias

typedef __attribute__((ext_vector_type(4))) float f32x4;
typedef __attribute__((ext_vector_type(8))) short short8;

// ---------------------------------------------------------------------------
// Kernel P (prep): CO = codebooks @ W_out slices ; BT = split-bf16 W^T ;
// zero flag counter. One block per (g,n) = 256 blocks x 256 threads.
// ---------------------------------------------------------------------------
__global__ __launch_bounds__(256) void prep_kernel(
    const float* __restrict__ codebooks,  // [2][128][128]
    const float* __restrict__ W_out,      // [256][256]
    const float* __restrict__ Wl,         // [2][128 k][128 n]
    float* __restrict__ CO,               // [2][128][256]
    short* __restrict__ BT,               // [2 lev][2 g][128 n][128 k]
    int* __restrict__ flag_count)
{
    const int gn  = blockIdx.x;           // g*128 + n
    const int g   = gn >> 7;
    const int tid = threadIdx.x;
    __shared__ float cb[DDIM];
    if (tid < DDIM) cb[tid] = codebooks[gn * DDIM + tid];
    if (tid >= 128) {
        const int k = tid - 128;
        const int n = gn & 127;
        const float x = Wl[((size_t)g * DDIM + k) * NN + n];
        const unsigned u = __float_as_uint(x);
        const float hi = __uint_as_float(u & 0xffff0000u);
        const unsigned u2 = __float_as_uint(x - hi);   // exact residual
        BT[(size_t)g * 16384 + n * 128 + k] = (short)(u >> 16);
        BT[32768 + (size_t)g * 16384 + n * 128 + k] = (short)(u2 >> 16);
    }
    if (gn == 0 && tid == 0) *flag_count = 0;
    __syncthreads();
    float acc = 0.f;
    const float* wcol = W_out + (g * DDIM) * EDIM + tid;
#pragma unroll 4
    for (int d = 0; d < DDIM; ++d) acc += cb[d] * wcol[d * EDIM];
    CO[gn * EDIM + tid] = acc;
}

// ---------------------------------------------------------------------------
// Kernel M (main v17): ALL global reads coalesced. Diagnosis r0-r15: F and
// gumbel loads were 64-way gathers (token in low lane bits -> consecutive
// lanes 1KB apart), capping effective read BW at ~2.76 TB/s in every variant
// (the shared ~97-105us wall); the one coalesced kernel (out) runs ~7 TB/s.
// Structure = r11 (verified): block 512 thr = 8 waves (wave = 16-n tile),
// ONE group, 256 tokens over 4 stages of 64; W in registers (32 VGPR);
// F split once to 2 bf16 planes in LDS. NEW: gumbel staged through LDS too
// (thread (tok,chunk) loads 64B F + 64B G contiguous; G raw in 132-float
// padded rows), epilogue reads G from LDS. Next-stage loads are asm-pinned
// (compiler sinks plain-C prefetch: r5-r14) and issued at compute start;
// one vmcnt(0)+sched_barrier per stage at stage top (rule #18).
// Numerics byte-identical to r5-r15 (same split, TAU, argmax, fixup).
// ---------------------------------------------------------------------------
__global__ __launch_bounds__(512) void pq_v17_kernel(
    const float* __restrict__ features,   // [T][256]
    const float* __restrict__ gumbel,     // [T][2][128]
    const short* __restrict__ BT,         // [2 lev][2 g][128 n][128 k]
    const float* __restrict__ bl,         // [2][128]
    float* __restrict__ idx_f,            // [T][2] float-encoded indices
    int* __restrict__ flag_count,
    int* __restrict__ flag_list)
{
    __shared__ short8 Flds[2048];              // 32 KB: [lev][tok][chunk ^ (tok&7)]
    __shared__ __align__(16) float Glds[64 * GROW];  // 33 KB padded gumbel
    __shared__ float pm1s[8][64];
    __shared__ float pm2s[8][64];
    __shared__ int   pi1s[8][64];

    const int tid  = threadIdx.x;
    const int g    = blockIdx.x & 1;
    const int span = blockIdx.x >> 1;     // 0..511
    const int w    = tid >> 6;            // wave = n-tile 0..7
    const int l    = tid & 63;
    const int q    = l & 15;              // token col / B row
    const int h    = l >> 4;              // k-octet / D-subrow
    const int n0   = w * 16;
    const int tb0  = span * 256;

    // ---- persistent W fragments: lane (q,h) holds W[n0+q][ks*32+h*8..+7]
    const short* bt1 = BT + (size_t)g * 16384 + (n0 + q) * 128 + h * 8;
    short8 A1[4], A2[4];
#pragma unroll
    for (int ks = 0; ks < 4; ++ks) {
        A1[ks] = *reinterpret_cast<const short8*>(bt1 + ks * 32);
        A2[ks] = *reinterpret_cast<const short8*>(bt1 + 32768 + ks * 32);
    }
    const f32x4 bv = *reinterpret_cast<const f32x4*>(bl + g * NN + n0 + h * 4);

    // staging role: thread = (stok, skc); 64B F + 64B G contiguous per thread
    const int stok = tid >> 3;            // 0..63
    const int skc  = tid & 7;             // 0..7 (16-f32 chunks)
    const int swz  = stok & 7;

    const float* fstage = features + (size_t)(tb0 + stok) * FDIM + g * DDIM + skc * 16;
    const float* gstage = gumbel + ((size_t)(tb0 + stok) * NG + g) * NN + skc * 16;

    f32x4 Fr[4], Gr[4];

#define GLOAD(dst, ptr) \
    asm volatile("global_load_dwordx4 %0, %1, off" : "=v"(dst) : "v"(ptr))
#define VWAIT0() do { \
    asm volatile("s_waitcnt vmcnt(0)" ::: "memory"); \
    __builtin_amdgcn_sched_barrier(0); } while (0)

    // ---- prologue: issue stage-0 loads (coalesced, asm-pinned)
    GLOAD(Fr[0], fstage);     GLOAD(Fr[1], fstage + 4);
    GLOAD(Fr[2], fstage + 8); GLOAD(Fr[3], fstage + 12);
    GLOAD(Gr[0], gstage);     GLOAD(Gr[1], gstage + 4);
    GLOAD(Gr[2], gstage + 8); GLOAD(Gr[3], gstage + 12);

#pragma unroll
    for (int st = 0; st < 4; ++st) {
        VWAIT0();   // Fr/Gr(st) landed (issued during previous compute phase)

        // ---- split F(st) to two bf16 planes (exact; same as r11)
        short8 SH0, SH1, SL0, SL1;
#pragma unroll
        for (int e = 0; e < 4; ++e) {
            unsigned u; float hi;
            u = __float_as_uint(Fr[0][e]); hi = __uint_as_float(u & 0xffff0000u);
            SH0[e]     = (short)(u >> 16); SL0[e]     = (short)(__float_as_uint(Fr[0][e] - hi) >> 16);
            u = __float_as_uint(Fr[1][e]); hi = __uint_as_float(u & 0xffff0000u);
            SH0[4 + e] = (short)(u >> 16); SL0[4 + e] = (short)(__float_as_uint(Fr[1][e] - hi) >> 16);
            u = __float_as_uint(Fr[2][e]); hi = __uint_as_float(u & 0xffff0000u);
            SH1[e]     = (short)(u >> 16); SL1[e]     = (short)(__float_as_uint(Fr[2][e] - hi) >> 16);
            u = __float_as_uint(Fr[3][e]); hi = __uint_as_float(u & 0xffff0000u);
            SH1[4 + e] = (short)(u >> 16); SL1[4 + e] = (short)(__float_as_uint(Fr[3][e] - hi) >> 16);
        }

        __syncthreads();   // barrier-1: prev compute done reading Flds/Glds

        // ---- ds_write F planes (r11 verified layout) + G raw (padded rows)
        {
            short8* rowHi = Flds + stok * 16;
            short8* rowLo = Flds + 1024 + stok * 16;
            rowHi[(2 * skc)     ^ swz] = SH0;
            rowHi[(2 * skc + 1) ^ swz] = SH1;
            rowLo[(2 * skc)     ^ swz] = SL0;
            rowLo[(2 * skc + 1) ^ swz] = SL1;
            float* grp = Glds + stok * GROW + skc * 16;
            *reinterpret_cast<f32x4*>(grp)      = Gr[0];
            *reinterpret_cast<f32x4*>(grp + 4)  = Gr[1];
            *reinterpret_cast<f32x4*>(grp + 8)  = Gr[2];
            *reinterpret_cast<f32x4*>(grp + 12) = Gr[3];
        }

        // ---- combine prev stage's partials (race-safe slot: between barriers)
        if (st > 0 && tid < 64) {
            float c1 = pm1s[0][tid], c2 = pm2s[0][tid];
            int   ci = pi1s[0][tid];
#pragma unroll
            for (int p = 1; p < 8; ++p) {
                const float a1 = pm1s[p][tid];
                const float a2 = pm2s[p][tid];
                const int   ai = pi1s[p][tid];
                if (a1 > c1)      { c2 = fmaxf(c1, a2); c1 = a1; ci = ai; }
                else if (a1 < c1) { c2 = fmaxf(c2, a1); }
                else              { c2 = c1; ci = min(ci, ai); }
            }
            const int t = tb0 + (st - 1) * 64 + tid;
            idx_f[(size_t)t * NG + g] = (float)ci;
            if (c1 - c2 < TAU) {
                const int p = atomicAdd(flag_count, 1);
                if (p < CAP) flag_list[p] = t * NG + g;
            }
        }

        __syncthreads();   // barrier-2: staging visible, combine reads done

        // ---- compute-window start: issue next stage's loads (hidden under MFMA)
        if (st < 3) {
            const float* fp = fstage + (size_t)(st + 1) * 64 * FDIM;
            const float* gp = gstage + (size_t)(st + 1) * 64 * NG * NN;
            GLOAD(Fr[0], fp);     GLOAD(Fr[1], fp + 4);
            GLOAD(Fr[2], fp + 8); GLOAD(Fr[3], fp + 12);
            GLOAD(Gr[0], gp);     GLOAD(Gr[1], gp + 4);
            GLOAD(Gr[2], gp + 8); GLOAD(Gr[3], gp + 12);
        }

        // ---- compute: 4 subtiles of 16 tokens (B from LDS, W in regs)
#pragma unroll
        for (int s = 0; s < 4; ++s) {
            const int rbase = (s * 16 + q) * 16;
            f32x4 acc = (f32x4){0.f, 0.f, 0.f, 0.f};
#pragma unroll
            for (int ks = 0; ks < 4; ++ks) {
                const int ci0 = (ks * 4 + h) ^ (q & 7);
                const short8 B1 = Flds[rbase + ci0];
                const short8 B2 = Flds[1024 + rbase + ci0];
                acc = __builtin_amdgcn_mfma_f32_16x16x32_bf16(A1[ks], B1, acc, 0, 0, 0);
                acc = __builtin_amdgcn_mfma_f32_16x16x32_bf16(A2[ks], B1, acc, 0, 0, 0);
                acc = __builtin_amdgcn_mfma_f32_16x16x32_bf16(A1[ks], B2, acc, 0, 0, 0);
            }

            // gumbel from LDS (was a 64-way global gather in r5-r15)
            const f32x4 gvv = *reinterpret_cast<const f32x4*>(
                &Glds[(s * 16 + q) * GROW + n0 + h * 4]);

            // per-lane top-2 over its 4 n-values
            float m1 = -3.4e38f, m2 = -3.4e38f;
            int   i1 = 0;
#pragma unroll
            for (int r = 0; r < 4; ++r) {
                const float vv = acc[r] + bv[r] + gvv[r];
                const int   n  = n0 + h * 4 + r;
                if (vv > m1) { m2 = m1; m1 = vv; i1 = n; }
                else         { m2 = fmaxf(m2, vv); }
            }
            // combine the 4 h-lanes sharing this token
#pragma unroll
            for (int off = 16; off < 64; off <<= 1) {
                const float om1 = __shfl_xor(m1, off);
                const int   oi1 = __shfl_xor(i1, off);
                const float om2 = __shfl_xor(m2, off);
                if (om1 > m1)      { m2 = fmaxf(m1, om2); m1 = om1; i1 = oi1; }
                else if (om1 < m1) { m2 = fmaxf(m2, om1); }
                else               { m2 = m1; i1 = min(i1, oi1); }
            }
            if (h == 0) {
                pm1s[w][s * 16 + q] = m1;
                pm2s[w][s * 16 + q] = m2;
                pi1s[w][s * 16 + q] = i1;
            }
        }
    }
#undef GLOAD
#undef VWAIT0

    // ---- final combine for stage 3
    __syncthreads();
    if (tid < 64) {
        float c1 = pm1s[0][tid], c2 = pm2s[0][tid];
        int   ci = pi1s[0][tid];
#pragma unroll
        for (int p = 1; p < 8; ++p) {
            const float a1 = pm1s[p][tid];
            const float a2 = pm2s[p][tid];
            const int   ai = pi1s[p][tid];
            if (a1 > c1)      { c2 = fmaxf(c1, a2); c1 = a1; ci = ai; }
            else if (a1 < c1) { c2 = fmaxf(c2, a1); }
            else              { c2 = c1; ci = min(ci, ai); }
        }
        const int t = tb0 + 3 * 64 + tid;
        idx_f[(size_t)t * NG + g] = (float)ci;
        if (c1 - c2 < TAU) {
            const int p = atomicAdd(flag_count, 1);
            if (p < CAP) flag_list[p] = t * NG + g;
        }
    }
}

// ---------------------------------------------------------------------------
// Kernel F (fixup): exact sequential-f32 fmaf recompute for flagged (t,g).
// ---------------------------------------------------------------------------
__global__ __launch_bounds__(128) void fixup_kernel(
    const float* __restrict__ features,
    const float* __restrict__ gumbel,
    const float* __restrict__ Wl,         // [2][128 k][128 n]
    const float* __restrict__ bl,
    float* __restrict__ idx_f,
    const int* __restrict__ flag_count,
    const int* __restrict__ flag_list)
{
    __shared__ float sm[2];
    __shared__ int   si[2];
    int total = *flag_count;
    if (total > CAP) total = CAP;
    const int n = threadIdx.x;

    for (int e = blockIdx.x; e < total; e += gridDim.x) {
        const int code = flag_list[e];
        const int t = code >> 1, g = code & 1;
        const float* fpr = features + (size_t)t * FDIM + g * DDIM;
        const float* wp  = Wl + (size_t)g * DDIM * NN + n;
        float dot = 0.f;
#pragma unroll 8
        for (int k = 0; k < DDIM; ++k) dot = fmaf(fpr[k], wp[(size_t)k * NN], dot);
        const float v = (dot + bl[g * NN + n]) + gumbel[((size_t)t * NG + g) * NN + n];

        float m = v; int bi = n;
#pragma unroll
        for (int off = 1; off < 64; off <<= 1) {
            const float om = __shfl_xor(m, off);
            const int   ob = __shfl_xor(bi, off);
            if (om > m || (om == m && ob < bi)) { m = om; bi = ob; }
        }
        if ((n & 63) == 0) { sm[n >> 6] = m; si[n >> 6] = bi; }
        __syncthreads();
        if (n == 0) {
            const float mA = sm[0], mB = sm[1];
            const int bA = si[0], bB = si[1];
            const int best = (mB > mA || (mB == mA && bB < bA)) ? bB : bA;
            idx_f[code] = (float)best;
        }
        __syncthreads();
    }
}

// ---------------------------------------------------------------------------
// Kernel C: out[t][e] = CO[0][i0][e] + CO[1][i1][e] + b_out[e]
// ---------------------------------------------------------------------------
__global__ __launch_bounds__(256) void out_kernel(
    const float* __restrict__ CO,      // [2][128][256]
    const float* __restrict__ b_out,   // [256]
    const float* __restrict__ idx_f,   // [T][2] float-encoded
    float* __restrict__ out)           // [T][256]
{
    const int tid = threadIdx.x;
    const int e4  = tid & 63;    // float4 index in e
    const int ts  = tid >> 6;    // 0..3
    const int tbase = blockIdx.x * 16;
    const float4 b = *reinterpret_cast<const float4*>(b_out + e4 * 4);

#pragma unroll
    for (int it = 0; it < 4; ++it) {
        const int t  = tbase + it * 4 + ts;
        const int i0 = (int)idx_f[t * NG + 0];
        const int i1 = (int)idx_f[t * NG + 1];
        const float4 c0 = *reinterpret_cast<const float4*>(CO + (size_t)i0 * EDIM + e4 * 4);
        const float4 c1 = *reinterpret_cast<const float4*>(CO + (size_t)(NN + i1) * EDIM + e4 * 4);
        float4 o;
        o.x = c0.x + c1.x + b.x;
        o.y = c0.y + c1.y + b.y;
        o.z = c0.z + c1.z + b.z;
        o.w = c0.w + c1.w + b.w;
        *reinterpret_cast<float4*>(out + (size_t)t * EDIM + e4 * 4) = o;
    }
}

// ---------------------------------------------------------------------------
extern "C" void kernel_launch(void* const* d_in, const int* in_sizes, int n_in,
                              void* d_out, int out_size, void* d_ws, size_t ws_size,
                              hipStream_t stream) {
    const float* features  = (const float*)d_in[0];  // [32,4096,256]
    const float* gumbel    = (const float*)d_in[1];  // [32,4096,2,128]
    const float* Wl        = (const float*)d_in[2];  // [2,128,128]
    const float* bl        = (const float*)d_in[3];  // [2,128]
    const float* codebooks = (const float*)d_in[4];  // [2,128,128]
    const float* W_out     = (const float*)d_in[5];  // [256,256]
    const float* b_out     = (const float*)d_in[6];  // [256]

    float* out   = (float*)d_out;                    // [T,256]
    float* idx_f = out + (size_t)T_TOTAL * EDIM;     // [T,2] float-encoded indices

    // ws layout: CO (256KB) | BT (128KB) | flag_count (pad 256B) | flag_list (64KB)
    char* ws = (char*)d_ws;
    float* CO         = (float*)ws;                        // 262144 B
    short* BT         = (short*)(ws + 262144);             // 131072 B
    int*   flag_count = (int*)(ws + 262144 + 131072);      // @393216
    int*   flag_list  = (int*)(ws + 393216 + 256);         // @393472, 64KB

    prep_kernel<<<NG * NN, 256, 0, stream>>>(codebooks, W_out, Wl, CO, BT, flag_count);
    pq_v17_kernel<<<1024, 512, 0, stream>>>(
        features, gumbel, BT, bl, idx_f, flag_count, flag_list);
    fixup_kernel<<<1024, 128, 0, stream>>>(
        features, gumbel, Wl, bl, idx_f, flag_count, flag_list);
    out_kernel<<<T_TOTAL / 16, 256, 0, stream>>>(CO, b_out, idx_f, out);
}